// Round 5
// baseline (276.286 us; speedup 1.0000x reference)
//
#include <hip/hip_runtime.h>
#include <hip/hip_bf16.h>
#include <stdint.h>

#define SS 8192
#define DD 1024
#define RR 16
#define OO 512

typedef __bf16 bf16_8 __attribute__((ext_vector_type(8)));
typedef float f32_4 __attribute__((ext_vector_type(4)));
typedef int i32_4 __attribute__((ext_vector_type(4)));

typedef __attribute__((address_space(1))) void g1_void;
typedef __attribute__((address_space(3))) void lds_void;

#define L2E 1.44269504f

__device__ __forceinline__ void gload_lds16(const void* g, void* l) {
  __builtin_amdgcn_global_load_lds((g1_void*)(uintptr_t)g,
                                   (lds_void*)(uint32_t)(uintptr_t)l, 16, 0, 0);
}

// Per-row absmax quantization to int8 + zero d_out.
// One block per row: rows 0..8191 = X, 8192..16383 = W. Row = 1024 f32.
__global__ __launch_bounds__(256) void somfnn_quant(
    const float* __restrict__ X, const float* __restrict__ W,
    char* __restrict__ Xq, char* __restrict__ Wq,
    float* __restrict__ sX, float* __restrict__ sW, float4* __restrict__ out) {
  __shared__ float red[4];
  const int r = blockIdx.x;
  const int tid = threadIdx.x;
  const bool isX = r < SS;
  const float* src = isX ? (X + (size_t)r * DD) : (W + (size_t)(r - SS) * DD);
  char* dst = isX ? (Xq + (size_t)r * DD) : (Wq + (size_t)(r - SS) * DD);

  float4 v = ((const float4*)src)[tid];
  float m = fmaxf(fmaxf(fabsf(v.x), fabsf(v.y)), fmaxf(fabsf(v.z), fabsf(v.w)));
#pragma unroll
  for (int off = 32; off > 0; off >>= 1) m = fmaxf(m, __shfl_xor(m, off, 64));
  if ((tid & 63) == 0) red[tid >> 6] = m;
  __syncthreads();
  m = fmaxf(fmaxf(red[0], red[1]), fmaxf(red[2], red[3]));
  m = fmaxf(m, 1e-20f);

  const float inv = 127.0f / m;
  int q0 = __float2int_rn(v.x * inv);
  int q1 = __float2int_rn(v.y * inv);
  int q2 = __float2int_rn(v.z * inv);
  int q3 = __float2int_rn(v.w * inv);
  int packed = (q0 & 0xff) | ((q1 & 0xff) << 8) | ((q2 & 0xff) << 16) | ((q3 & 0xff) << 24);
  ((int*)dst)[tid] = packed;

  if (tid == 0) {
    if (isX) sX[r] = m / 127.0f;
    else sW[r - SS] = m / 127.0f;
  }
  if (tid < 64) {
    float4 z{0.f, 0.f, 0.f, 0.f};
    out[(size_t)r * 64 + tid] = z;
  }
}

// i8 GEMM, A (X) via async-LDS double-buffer, B (W) streamed DIRECTLY from
// global (per-XCD L2-resident: swizzle fixes (rhalf,ob) per XCD -> B working
// set = 8 rules * 128 cols * 1KB = 1MB). Deletes half the LDS traffic
// (was 96KB/block-step, now 48KB). B frag = 16B contiguous per lane
// (4 q-lanes form 64B sectors of one W row).
__global__ __launch_bounds__(256, 2) void somfnn_gemm_i8(
    const char* __restrict__ Xq, const char* __restrict__ Wq,
    const float* __restrict__ sX, const float* __restrict__ sW,
    const float* __restrict__ bias_g, const float* __restrict__ lam_g,
    float* __restrict__ out) {
  constexpr int BM = 128, BN = 128, BK = 128;
  constexpr int TILEB = BM * BK;        // 16KB A buffer
  constexpr int NSTEP = 8 * (DD / BK);  // 8 rules * 8 k-tiles = 64

  __shared__ __align__(16) char lds_a[2][TILEB];
  __shared__ float lds_bias[8 * BN];   // -b * log2e, per rule
  __shared__ float lds_lam[8 * BM];
  __shared__ float lds_sB[8 * BN];     // W-row scales, per rule
  __shared__ float lds_sA[BM];         // X-row scales

  const int tid = threadIdx.x;
  const int bid = blockIdx.x;

  const int l = tid & 63;
  const int w = tid >> 6;
  const int lane15 = l & 15;
  const int q = l >> 4;
  const int wm = w >> 1;   // 2x2 wave grid, each wave 64x64
  const int wn = w & 1;

  const int rhalf = bid & 1;          // XCD swizzle: (rhalf, ob) const per XCD
  const int ob = (bid >> 1) & 3;
  const int sb = bid >> 3;
  const int s0 = sb * BM;
  const int o0 = ob * BN;
  const int r0 = rhalf * 8;

  for (int idx = tid; idx < 8 * BN; idx += 256) {
    int rr = idx >> 7, j = idx & 127;
    lds_bias[idx] = -L2E * bias_g[(r0 + rr) * OO + o0 + j];
    lds_sB[idx] = sW[(r0 + rr) * OO + o0 + j];
  }
  for (int idx = tid; idx < 8 * BM; idx += 256) {
    int rr = idx >> 7, i = idx & 127;
    lds_lam[idx] = lam_g[(s0 + i) * RR + (r0 + rr)];
  }
  if (tid < BM) lds_sA[tid] = sX[s0 + tid];

  // A staging: 4 chunks of 16B per thread per step (XOR swizzle
  // chunk = k16 ^ (row&7): conflict-free fill AND conflict-free frag reads)
  int goffs[4];
#pragma unroll
  for (int i = 0; i < 4; ++i) {
    int c = (w * 4 + i) * 64 + l;
    int row = c >> 3;
    int k16 = (c & 7) ^ (row & 7);
    goffs[i] = row * DD + k16 * 16;
  }

  // A fragment LDS byte offsets for ks=0; ks=1 is ^64 (chunk ^4)
  int afo[4];
#pragma unroll
  for (int t = 0; t < 4; ++t) {
    int ra = wm * 64 + t * 16 + lane15;
    afo[t] = ra * BK + ((q ^ (ra & 7)) * 16);
  }

  // B direct-load per-lane byte offset within the rule's W slice:
  // row (wn*64 + t*16 + lane15) of [128 x 1024B], chunk q
  int boff[4];
#pragma unroll
  for (int t = 0; t < 4; ++t) boff[t] = (wn * 64 + t * 16 + lane15) * DD + q * 16;

  auto issue_a = [&](int step, int buf) {
    int rl = step >> 3, kt = step & 7;
    const char* ga = Xq + (size_t)s0 * DD + rl * 0 + kt * BK;  // A independent of rule
#pragma unroll
    for (int i = 0; i < 4; ++i)
      gload_lds16(ga + goffs[i], &lds_a[buf][(w * 4 + i) * 1024]);
  };

  i32_4 acc[4][4];
  f32_4 oacc[4][4];
#pragma unroll
  for (int mi = 0; mi < 4; ++mi)
#pragma unroll
    for (int ni = 0; ni < 4; ++ni) {
      acc[mi][ni] = i32_4{0, 0, 0, 0};
      oacc[mi][ni] = f32_4{0.f, 0.f, 0.f, 0.f};
    }

  issue_a(0, 0);
  __syncthreads();

  for (int step = 0; step < NSTEP; ++step) {
    const int cur = step & 1;
    const bool more = (step + 1) < NSTEP;
    if (more) issue_a(step + 1, cur ^ 1);

    const int rl = step >> 3, kt = step & 7;
    const char* Bg = Wq + ((size_t)(r0 + rl) * OO + o0) * DD + kt * BK;
    const char* A = lds_a[cur];
#pragma unroll
    for (int ks = 0; ks < 2; ++ks) {
      const int xr = ks ? 64 : 0;
      i32_4 av[4], bv[4];
#pragma unroll
      for (int ni = 0; ni < 4; ++ni)
        bv[ni] = *(const i32_4*)(Bg + boff[ni] + ks * 64);
#pragma unroll
      for (int mi = 0; mi < 4; ++mi) av[mi] = *(const i32_4*)(A + (afo[mi] ^ xr));
#pragma unroll
      for (int mi = 0; mi < 4; ++mi)
#pragma unroll
        for (int ni = 0; ni < 4; ++ni)
          acc[mi][ni] =
              __builtin_amdgcn_mfma_i32_16x16x64_i8(av[mi], bv[ni], acc[mi][ni], 0, 0, 0);
    }

    if ((step & 7) == 7) {  // rule rl finished K: dequant + sigmoid + reduce
      float lsa[4][4], lamv[4][4];
#pragma unroll
      for (int mi = 0; mi < 4; ++mi)
#pragma unroll
        for (int v = 0; v < 4; ++v) {
          int ridx = wm * 64 + mi * 16 + q * 4 + v;
          lsa[mi][v] = -L2E * lds_sA[ridx];
          lamv[mi][v] = lds_lam[rl * BM + ridx];
        }
#pragma unroll
      for (int ni = 0; ni < 4; ++ni) {
        const int cidx = wn * 64 + ni * 16 + lane15;
        const float nb = lds_bias[rl * BN + cidx];
        const float sbv = lds_sB[rl * BN + cidx];
#pragma unroll
        for (int mi = 0; mi < 4; ++mi)
#pragma unroll
          for (int v = 0; v < 4; ++v) {
            float t = __builtin_fmaf((float)acc[mi][ni][v], lsa[mi][v] * sbv, nb);
            float e = __builtin_amdgcn_exp2f(t);
            float h = __builtin_amdgcn_rcpf(1.0f + e);
            oacc[mi][ni][v] = __builtin_fmaf(lamv[mi][v], h, oacc[mi][ni][v]);
            acc[mi][ni][v] = 0;
          }
      }
    }
    __syncthreads();
  }

#pragma unroll
  for (int mi = 0; mi < 4; ++mi)
#pragma unroll
    for (int ni = 0; ni < 4; ++ni)
#pragma unroll
      for (int v = 0; v < 4; ++v) {
        int row = s0 + wm * 64 + mi * 16 + q * 4 + v;
        int col = o0 + wn * 64 + ni * 16 + lane15;
        atomicAdd(&out[row * OO + col], oacc[mi][ni][v]);
      }
}

// Fallback (ws too small): bf16 GEMM converting fp32 during LDS staging.
__global__ __launch_bounds__(256, 2) void somfnn_gemm_fb(
    const float* __restrict__ Xf32, const float* __restrict__ Wf32,
    const float* __restrict__ bias_g, const float* __restrict__ lam_g,
    float* __restrict__ out) {
  constexpr int BM = 128, BN = 128, BK = 64;
  constexpr int TILE = BM * BK;
  constexpr int NSTEP = 8 * (DD / BK);

  __shared__ __align__(16) __bf16 lds_a[2][TILE];
  __shared__ __align__(16) __bf16 lds_b[2][TILE];
  __shared__ float lds_bias[8 * BN];
  __shared__ float lds_lam[8 * BM];

  const int tid = threadIdx.x;
  const int bid = blockIdx.x;
  const int l = tid & 63;
  const int w = tid >> 6;
  const int lane15 = l & 15;
  const int q = l >> 4;
  const int wm = w >> 1;
  const int wn = w & 1;

  const int rhalf = bid & 1;
  const int ob = (bid >> 1) & 3;
  const int sb = bid >> 3;
  const int s0 = sb * BM;
  const int o0 = ob * BN;
  const int r0 = rhalf * 8;

  for (int idx = tid; idx < 8 * BN; idx += 256) {
    int rr = idx >> 7, j = idx & 127;
    lds_bias[idx] = -L2E * bias_g[(r0 + rr) * OO + o0 + j];
  }
  for (int idx = tid; idx < 8 * BM; idx += 256) {
    int rr = idx >> 7, i = idx & 127;
    lds_lam[idx] = lam_g[(s0 + i) * RR + (r0 + rr)];
  }

  int goffs[4], coffs[4];
#pragma unroll
  for (int i = 0; i < 4; ++i) {
    int c = (w * 4 + i) * 64 + l;
    int row = c >> 3;
    int k8 = (c & 7) ^ (row & 7);
    goffs[i] = row * DD + k8 * 8;
    coffs[i] = c * 8;
  }
  int afo[4], bfo[4];
#pragma unroll
  for (int t = 0; t < 4; ++t) {
    int ra = wm * 64 + t * 16 + lane15;
    afo[t] = (ra * 8 + (q ^ (ra & 7))) * 8;
    int rb = wn * 64 + t * 16 + lane15;
    bfo[t] = (rb * 8 + (q ^ (rb & 7))) * 8;
  }

  float4 ra_[4][2], rb_[4][2];
  auto issue_fb = [&](int step) {
    int rl = step >> 4, kt = step & 15;
    const float* ga = Xf32 + s0 * DD + kt * BK;
    const float* gb = Wf32 + ((r0 + rl) * OO + o0) * DD + kt * BK;
#pragma unroll
    for (int i = 0; i < 4; ++i) {
      const float4* p = (const float4*)(ga + goffs[i]);
      ra_[i][0] = p[0]; ra_[i][1] = p[1];
      const float4* pb = (const float4*)(gb + goffs[i]);
      rb_[i][0] = pb[0]; rb_[i][1] = pb[1];
    }
  };
  auto commit_fb = [&](int buf) {
#pragma unroll
    for (int i = 0; i < 4; ++i) {
      bf16_8 t;
      t[0] = (__bf16)ra_[i][0].x; t[1] = (__bf16)ra_[i][0].y;
      t[2] = (__bf16)ra_[i][0].z; t[3] = (__bf16)ra_[i][0].w;
      t[4] = (__bf16)ra_[i][1].x; t[5] = (__bf16)ra_[i][1].y;
      t[6] = (__bf16)ra_[i][1].z; t[7] = (__bf16)ra_[i][1].w;
      *(bf16_8*)&lds_a[buf][coffs[i]] = t;
      bf16_8 u;
      u[0] = (__bf16)rb_[i][0].x; u[1] = (__bf16)rb_[i][0].y;
      u[2] = (__bf16)rb_[i][0].z; u[3] = (__bf16)rb_[i][0].w;
      u[4] = (__bf16)rb_[i][1].x; u[5] = (__bf16)rb_[i][1].y;
      u[6] = (__bf16)rb_[i][1].z; u[7] = (__bf16)rb_[i][1].w;
      *(bf16_8*)&lds_b[buf][coffs[i]] = u;
    }
  };

  f32_4 acc[4][4], oacc[4][4];
#pragma unroll
  for (int mi = 0; mi < 4; ++mi)
#pragma unroll
    for (int ni = 0; ni < 4; ++ni) {
      acc[mi][ni] = f32_4{0.f, 0.f, 0.f, 0.f};
      oacc[mi][ni] = f32_4{0.f, 0.f, 0.f, 0.f};
    }

  issue_fb(0);
  commit_fb(0);
  __syncthreads();

  for (int step = 0; step < NSTEP; ++step) {
    const int cur = step & 1;
    const bool more = (step + 1) < NSTEP;
    if (more) issue_fb(step + 1);

    const __bf16* A = lds_a[cur];
    const __bf16* B = lds_b[cur];
#pragma unroll
    for (int ks = 0; ks < 2; ++ks) {
      const int xr = ks ? 32 : 0;
      bf16_8 av[4], bv[4];
#pragma unroll
      for (int mi = 0; mi < 4; ++mi) av[mi] = *(const bf16_8*)(A + (afo[mi] ^ xr));
#pragma unroll
      for (int ni = 0; ni < 4; ++ni) bv[ni] = *(const bf16_8*)(B + (bfo[ni] ^ xr));
#pragma unroll
      for (int mi = 0; mi < 4; ++mi)
#pragma unroll
        for (int ni = 0; ni < 4; ++ni)
          acc[mi][ni] =
              __builtin_amdgcn_mfma_f32_16x16x32_bf16(av[mi], bv[ni], acc[mi][ni], 0, 0, 0);
    }
    if (more) commit_fb(cur ^ 1);

    if ((step & 15) == 15) {
      const int rl = step >> 4;
      float lamv[4][4];
#pragma unroll
      for (int mi = 0; mi < 4; ++mi)
#pragma unroll
        for (int v = 0; v < 4; ++v)
          lamv[mi][v] = lds_lam[rl * BM + wm * 64 + mi * 16 + q * 4 + v];
#pragma unroll
      for (int ni = 0; ni < 4; ++ni) {
        const float nb = lds_bias[rl * BN + wn * 64 + ni * 16 + lane15];
#pragma unroll
        for (int mi = 0; mi < 4; ++mi)
#pragma unroll
          for (int v = 0; v < 4; ++v) {
            float t = __builtin_fmaf(acc[mi][ni][v], -L2E, nb);
            float e = __builtin_amdgcn_exp2f(t);
            float h = __builtin_amdgcn_rcpf(1.0f + e);
            oacc[mi][ni][v] = __builtin_fmaf(lamv[mi][v], h, oacc[mi][ni][v]);
            acc[mi][ni][v] = 0.f;
          }
      }
    }
    __syncthreads();
  }

#pragma unroll
  for (int mi = 0; mi < 4; ++mi)
#pragma unroll
    for (int ni = 0; ni < 4; ++ni)
#pragma unroll
      for (int v = 0; v < 4; ++v) {
        int row = s0 + wm * 64 + mi * 16 + q * 4 + v;
        int col = o0 + wn * 64 + ni * 16 + lane15;
        atomicAdd(&out[row * OO + col], oacc[mi][ni][v]);
      }
}

extern "C" void kernel_launch(void* const* d_in, const int* in_sizes, int n_in,
                              void* d_out, int out_size, void* d_ws, size_t ws_size,
                              hipStream_t stream) {
  const float* X = (const float*)d_in[0];
  const float* W = (const float*)d_in[1];
  const float* b = (const float*)d_in[2];
  const float* lam = (const float*)d_in[3];
  float* out = (float*)d_out;

  // ws layout: Xq 8MB | Wq 8MB | sX 32KB | sW 32KB
  const size_t qbytes = (size_t)SS * DD;
  const size_t need = 2 * qbytes + 2 * (size_t)SS * sizeof(float);
  if (ws_size >= need) {
    char* Xq = (char*)d_ws;
    char* Wq = Xq + qbytes;
    float* sX = (float*)(Wq + qbytes);
    float* sW = sX + SS;
    somfnn_quant<<<dim3(2 * SS), dim3(256), 0, stream>>>(X, W, Xq, Wq, sX, sW, (float4*)out);
    somfnn_gemm_i8<<<dim3(512), dim3(256), 0, stream>>>(Xq, Wq, sX, sW, b, lam, out);
  } else {
    hipMemsetAsync(out, 0, (size_t)SS * OO * sizeof(float), stream);
    somfnn_gemm_fb<<<dim3(512), dim3(256), 0, stream>>>(X, W, b, lam, out);
  }
}

// Round 6
// 197.975 us; speedup vs baseline: 1.3956x; 1.3956x over previous
//
#include <hip/hip_runtime.h>
#include <hip/hip_bf16.h>
#include <stdint.h>

#define SS 8192
#define DD 1024
#define RR 16
#define OO 512

typedef __bf16 bf16_8 __attribute__((ext_vector_type(8)));
typedef float f32_4 __attribute__((ext_vector_type(4)));
typedef int i32_4 __attribute__((ext_vector_type(4)));

typedef __attribute__((address_space(1))) void g1_void;
typedef __attribute__((address_space(3))) void lds_void;

#define L2E 1.44269504f

__device__ __forceinline__ void gload_lds16(const void* g, void* l) {
  __builtin_amdgcn_global_load_lds((g1_void*)(uintptr_t)g,
                                   (lds_void*)(uint32_t)(uintptr_t)l, 16, 0, 0);
}

// Per-row absmax quantization to int8 + zero d_out.
// One block per row: rows 0..8191 = X, 8192..16383 = W. Row = 1024 f32.
__global__ __launch_bounds__(256) void somfnn_quant(
    const float* __restrict__ X, const float* __restrict__ W,
    char* __restrict__ Xq, char* __restrict__ Wq,
    float* __restrict__ sX, float* __restrict__ sW, float4* __restrict__ out) {
  __shared__ float red[4];
  const int r = blockIdx.x;
  const int tid = threadIdx.x;
  const bool isX = r < SS;
  const float* src = isX ? (X + (size_t)r * DD) : (W + (size_t)(r - SS) * DD);
  char* dst = isX ? (Xq + (size_t)r * DD) : (Wq + (size_t)(r - SS) * DD);

  float4 v = ((const float4*)src)[tid];
  float m = fmaxf(fmaxf(fabsf(v.x), fabsf(v.y)), fmaxf(fabsf(v.z), fabsf(v.w)));
#pragma unroll
  for (int off = 32; off > 0; off >>= 1) m = fmaxf(m, __shfl_xor(m, off, 64));
  if ((tid & 63) == 0) red[tid >> 6] = m;
  __syncthreads();
  m = fmaxf(fmaxf(red[0], red[1]), fmaxf(red[2], red[3]));
  m = fmaxf(m, 1e-20f);

  const float inv = 127.0f / m;
  int q0 = __float2int_rn(v.x * inv);
  int q1 = __float2int_rn(v.y * inv);
  int q2 = __float2int_rn(v.z * inv);
  int q3 = __float2int_rn(v.w * inv);
  int packed = (q0 & 0xff) | ((q1 & 0xff) << 8) | ((q2 & 0xff) << 16) | ((q3 & 0xff) << 24);
  ((int*)dst)[tid] = packed;

  if (tid == 0) {
    if (isX) sX[r] = m / 127.0f;
    else sW[r - SS] = m / 127.0f;
  }
  if (tid < 64) {
    float4 z{0.f, 0.f, 0.f, 0.f};
    out[(size_t)r * 64 + tid] = z;
  }
}

// i8 GEMM (R4 core: BOTH operands via async-LDS double-buffer — B-direct
// regressed in R5: per-MFMA global latency + vmcnt(0) barrier drain).
// NEW: L2-resident swizzle. xcd = bid&7 (round-robin dispatch); each XCD
// owns 8 consecutive s-tiles (A slice = 1 MB, L2-resident across all 8
// rule-passes) and spreads (ob, rhalf) internally (temporal B = ~1 MB/rule).
// Was: (rhalf,ob) fixed per XCD -> A working set 8 MB > 4 MB L2 -> staging
// drained from L3/HBM (FETCH 268 MB, ~900 cyc/step stall).
__global__ __launch_bounds__(256, 2) void somfnn_gemm_i8(
    const char* __restrict__ Xq, const char* __restrict__ Wq,
    const float* __restrict__ sX, const float* __restrict__ sW,
    const float* __restrict__ bias_g, const float* __restrict__ lam_g,
    float* __restrict__ out) {
  constexpr int BM = 128, BN = 128, BK = 128;
  constexpr int TILEB = BM * BK;        // 16KB per buffer
  constexpr int NSTEP = 8 * (DD / BK);  // 8 rules * 8 k-tiles = 64

  __shared__ __align__(16) char lds_a[2][TILEB];
  __shared__ __align__(16) char lds_b[2][TILEB];
  __shared__ float lds_bias[8 * BN];   // -b * log2e, per rule
  __shared__ float lds_lam[8 * BM];
  __shared__ float lds_sB[8 * BN];     // W-row scales, per rule
  __shared__ float lds_sA[BM];         // X-row scales

  const int tid = threadIdx.x;
  const int bid = blockIdx.x;

  const int l = tid & 63;
  const int w = tid >> 6;
  const int lane15 = l & 15;
  const int q = l >> 4;
  const int wm = w >> 1;   // 2x2 wave grid, each wave 64x64
  const int wn = w & 1;

  // L2-locality swizzle: XCD = bid % 8 owns s-tiles [xcd*8, xcd*8+8)
  const int xcd = bid & 7;
  const int chunk = bid >> 3;            // [0,64)
  const int sb = xcd * 8 + (chunk & 7);  // 8 s-tiles per XCD -> A 1MB L2-res
  const int ob = (chunk >> 3) & 3;
  const int rhalf = chunk >> 5;
  const int s0 = sb * BM;
  const int o0 = ob * BN;
  const int r0 = rhalf * 8;

  for (int idx = tid; idx < 8 * BN; idx += 256) {
    int rr = idx >> 7, j = idx & 127;
    lds_bias[idx] = -L2E * bias_g[(r0 + rr) * OO + o0 + j];
    lds_sB[idx] = sW[(r0 + rr) * OO + o0 + j];
  }
  for (int idx = tid; idx < 8 * BM; idx += 256) {
    int rr = idx >> 7, i = idx & 127;
    lds_lam[idx] = lam_g[(s0 + i) * RR + (r0 + rr)];
  }
  if (tid < BM) lds_sA[tid] = sX[s0 + tid];

  // staging: 4 chunks of 16B per thread per matrix per step (XOR swizzle
  // chunk = k16 ^ (row&7): conflict-free fill AND conflict-free frag reads)
  int goffs[4];
#pragma unroll
  for (int i = 0; i < 4; ++i) {
    int c = (w * 4 + i) * 64 + l;
    int row = c >> 3;
    int k16 = (c & 7) ^ (row & 7);
    goffs[i] = row * DD + k16 * 16;
  }

  // fragment LDS byte offsets for ks=0; ks=1 is ^64 (chunk ^4)
  int afo[4], bfo[4];
#pragma unroll
  for (int t = 0; t < 4; ++t) {
    int ra = wm * 64 + t * 16 + lane15;
    afo[t] = ra * BK + ((q ^ (ra & 7)) * 16);
    int rb = wn * 64 + t * 16 + lane15;
    bfo[t] = rb * BK + ((q ^ (rb & 7)) * 16);
  }

  auto issue_pre = [&](int step, int buf) {
    int rl = step >> 3, kt = step & 7;
    const char* ga = Xq + (size_t)s0 * DD + kt * BK;
    const char* gb = Wq + ((size_t)(r0 + rl) * OO + o0) * DD + kt * BK;
#pragma unroll
    for (int i = 0; i < 4; ++i)
      gload_lds16(ga + goffs[i], &lds_a[buf][(w * 4 + i) * 1024]);
#pragma unroll
    for (int i = 0; i < 4; ++i)
      gload_lds16(gb + goffs[i], &lds_b[buf][(w * 4 + i) * 1024]);
  };

  i32_4 acc[4][4];
  f32_4 oacc[4][4];
#pragma unroll
  for (int mi = 0; mi < 4; ++mi)
#pragma unroll
    for (int ni = 0; ni < 4; ++ni) {
      acc[mi][ni] = i32_4{0, 0, 0, 0};
      oacc[mi][ni] = f32_4{0.f, 0.f, 0.f, 0.f};
    }

  issue_pre(0, 0);
  __syncthreads();

  for (int step = 0; step < NSTEP; ++step) {
    const int cur = step & 1;
    const bool more = (step + 1) < NSTEP;
    if (more) issue_pre(step + 1, cur ^ 1);

    const char* A = lds_a[cur];
    const char* B = lds_b[cur];
#pragma unroll
    for (int ks = 0; ks < 2; ++ks) {
      const int xr = ks ? 64 : 0;
      i32_4 av[4], bv[4];
#pragma unroll
      for (int mi = 0; mi < 4; ++mi) av[mi] = *(const i32_4*)(A + (afo[mi] ^ xr));
#pragma unroll
      for (int ni = 0; ni < 4; ++ni) bv[ni] = *(const i32_4*)(B + (bfo[ni] ^ xr));
#pragma unroll
      for (int mi = 0; mi < 4; ++mi)
#pragma unroll
        for (int ni = 0; ni < 4; ++ni)
          acc[mi][ni] =
              __builtin_amdgcn_mfma_i32_16x16x64_i8(av[mi], bv[ni], acc[mi][ni], 0, 0, 0);
    }

    if ((step & 7) == 7) {  // rule rl finished K: dequant + sigmoid + reduce
      const int rl = step >> 3;
      float lsa[4][4], lamv[4][4];
#pragma unroll
      for (int mi = 0; mi < 4; ++mi)
#pragma unroll
        for (int v = 0; v < 4; ++v) {
          int ridx = wm * 64 + mi * 16 + q * 4 + v;
          lsa[mi][v] = -L2E * lds_sA[ridx];
          lamv[mi][v] = lds_lam[rl * BM + ridx];
        }
#pragma unroll
      for (int ni = 0; ni < 4; ++ni) {
        const int cidx = wn * 64 + ni * 16 + lane15;
        const float nb = lds_bias[rl * BN + cidx];
        const float sbv = lds_sB[rl * BN + cidx];
#pragma unroll
        for (int mi = 0; mi < 4; ++mi)
#pragma unroll
          for (int v = 0; v < 4; ++v) {
            float t = __builtin_fmaf((float)acc[mi][ni][v], lsa[mi][v] * sbv, nb);
            float e = __builtin_amdgcn_exp2f(t);
            float h = __builtin_amdgcn_rcpf(1.0f + e);
            oacc[mi][ni][v] = __builtin_fmaf(lamv[mi][v], h, oacc[mi][ni][v]);
            acc[mi][ni][v] = 0;
          }
      }
    }
    __syncthreads();
  }

#pragma unroll
  for (int mi = 0; mi < 4; ++mi)
#pragma unroll
    for (int ni = 0; ni < 4; ++ni)
#pragma unroll
      for (int v = 0; v < 4; ++v) {
        int row = s0 + wm * 64 + mi * 16 + q * 4 + v;
        int col = o0 + wn * 64 + ni * 16 + lane15;
        atomicAdd(&out[row * OO + col], oacc[mi][ni][v]);
      }
}

// Fallback (ws too small): bf16 GEMM converting fp32 during LDS staging.
__global__ __launch_bounds__(256, 2) void somfnn_gemm_fb(
    const float* __restrict__ Xf32, const float* __restrict__ Wf32,
    const float* __restrict__ bias_g, const float* __restrict__ lam_g,
    float* __restrict__ out) {
  constexpr int BM = 128, BN = 128, BK = 64;
  constexpr int TILE = BM * BK;
  constexpr int NSTEP = 8 * (DD / BK);

  __shared__ __align__(16) __bf16 lds_a[2][TILE];
  __shared__ __align__(16) __bf16 lds_b[2][TILE];
  __shared__ float lds_bias[8 * BN];
  __shared__ float lds_lam[8 * BM];

  const int tid = threadIdx.x;
  const int bid = blockIdx.x;
  const int l = tid & 63;
  const int w = tid >> 6;
  const int lane15 = l & 15;
  const int q = l >> 4;
  const int wm = w >> 1;
  const int wn = w & 1;

  const int xcd = bid & 7;
  const int chunk = bid >> 3;
  const int sb = xcd * 8 + (chunk & 7);
  const int ob = (chunk >> 3) & 3;
  const int rhalf = chunk >> 5;
  const int s0 = sb * BM;
  const int o0 = ob * BN;
  const int r0 = rhalf * 8;

  for (int idx = tid; idx < 8 * BN; idx += 256) {
    int rr = idx >> 7, j = idx & 127;
    lds_bias[idx] = -L2E * bias_g[(r0 + rr) * OO + o0 + j];
  }
  for (int idx = tid; idx < 8 * BM; idx += 256) {
    int rr = idx >> 7, i = idx & 127;
    lds_lam[idx] = lam_g[(s0 + i) * RR + (r0 + rr)];
  }

  int goffs[4], coffs[4];
#pragma unroll
  for (int i = 0; i < 4; ++i) {
    int c = (w * 4 + i) * 64 + l;
    int row = c >> 3;
    int k8 = (c & 7) ^ (row & 7);
    goffs[i] = row * DD + k8 * 8;
    coffs[i] = c * 8;
  }
  int afo[4], bfo[4];
#pragma unroll
  for (int t = 0; t < 4; ++t) {
    int ra = wm * 64 + t * 16 + lane15;
    afo[t] = (ra * 8 + (q ^ (ra & 7))) * 8;
    int rb = wn * 64 + t * 16 + lane15;
    bfo[t] = (rb * 8 + (q ^ (rb & 7))) * 8;
  }

  float4 ra_[4][2], rb_[4][2];
  auto issue_fb = [&](int step) {
    int rl = step >> 4, kt = step & 15;
    const float* ga = Xf32 + s0 * DD + kt * BK;
    const float* gb = Wf32 + ((r0 + rl) * OO + o0) * DD + kt * BK;
#pragma unroll
    for (int i = 0; i < 4; ++i) {
      const float4* p = (const float4*)(ga + goffs[i]);
      ra_[i][0] = p[0]; ra_[i][1] = p[1];
      const float4* pb = (const float4*)(gb + goffs[i]);
      rb_[i][0] = pb[0]; rb_[i][1] = pb[1];
    }
  };
  auto commit_fb = [&](int buf) {
#pragma unroll
    for (int i = 0; i < 4; ++i) {
      bf16_8 t;
      t[0] = (__bf16)ra_[i][0].x; t[1] = (__bf16)ra_[i][0].y;
      t[2] = (__bf16)ra_[i][0].z; t[3] = (__bf16)ra_[i][0].w;
      t[4] = (__bf16)ra_[i][1].x; t[5] = (__bf16)ra_[i][1].y;
      t[6] = (__bf16)ra_[i][1].z; t[7] = (__bf16)ra_[i][1].w;
      *(bf16_8*)&lds_a[buf][coffs[i]] = t;
      bf16_8 u;
      u[0] = (__bf16)rb_[i][0].x; u[1] = (__bf16)rb_[i][0].y;
      u[2] = (__bf16)rb_[i][0].z; u[3] = (__bf16)rb_[i][0].w;
      u[4] = (__bf16)rb_[i][1].x; u[5] = (__bf16)rb_[i][1].y;
      u[6] = (__bf16)rb_[i][1].z; u[7] = (__bf16)rb_[i][1].w;
      *(bf16_8*)&lds_b[buf][coffs[i]] = u;
    }
  };

  f32_4 acc[4][4], oacc[4][4];
#pragma unroll
  for (int mi = 0; mi < 4; ++mi)
#pragma unroll
    for (int ni = 0; ni < 4; ++ni) {
      acc[mi][ni] = f32_4{0.f, 0.f, 0.f, 0.f};
      oacc[mi][ni] = f32_4{0.f, 0.f, 0.f, 0.f};
    }

  issue_fb(0);
  commit_fb(0);
  __syncthreads();

  for (int step = 0; step < NSTEP; ++step) {
    const int cur = step & 1;
    const bool more = (step + 1) < NSTEP;
    if (more) issue_fb(step + 1);

    const __bf16* A = lds_a[cur];
    const __bf16* B = lds_b[cur];
#pragma unroll
    for (int ks = 0; ks < 2; ++ks) {
      const int xr = ks ? 32 : 0;
      bf16_8 av[4], bv[4];
#pragma unroll
      for (int mi = 0; mi < 4; ++mi) av[mi] = *(const bf16_8*)(A + (afo[mi] ^ xr));
#pragma unroll
      for (int ni = 0; ni < 4; ++ni) bv[ni] = *(const bf16_8*)(B + (bfo[ni] ^ xr));
#pragma unroll
      for (int mi = 0; mi < 4; ++mi)
#pragma unroll
        for (int ni = 0; ni < 4; ++ni)
          acc[mi][ni] =
              __builtin_amdgcn_mfma_f32_16x16x32_bf16(av[mi], bv[ni], acc[mi][ni], 0, 0, 0);
    }
    if (more) commit_fb(cur ^ 1);

    if ((step & 15) == 15) {
      const int rl = step >> 4;
      float lamv[4][4];
#pragma unroll
      for (int mi = 0; mi < 4; ++mi)
#pragma unroll
        for (int v = 0; v < 4; ++v)
          lamv[mi][v] = lds_lam[rl * BM + wm * 64 + mi * 16 + q * 4 + v];
#pragma unroll
      for (int ni = 0; ni < 4; ++ni) {
        const float nb = lds_bias[rl * BN + wn * 64 + ni * 16 + lane15];
#pragma unroll
        for (int mi = 0; mi < 4; ++mi)
#pragma unroll
          for (int v = 0; v < 4; ++v) {
            float t = __builtin_fmaf(acc[mi][ni][v], -L2E, nb);
            float e = __builtin_amdgcn_exp2f(t);
            float h = __builtin_amdgcn_rcpf(1.0f + e);
            oacc[mi][ni][v] = __builtin_fmaf(lamv[mi][v], h, oacc[mi][ni][v]);
            acc[mi][ni][v] = 0.f;
          }
      }
    }
    __syncthreads();
  }

#pragma unroll
  for (int mi = 0; mi < 4; ++mi)
#pragma unroll
    for (int ni = 0; ni < 4; ++ni)
#pragma unroll
      for (int v = 0; v < 4; ++v) {
        int row = s0 + wm * 64 + mi * 16 + q * 4 + v;
        int col = o0 + wn * 64 + ni * 16 + lane15;
        atomicAdd(&out[row * OO + col], oacc[mi][ni][v]);
      }
}

extern "C" void kernel_launch(void* const* d_in, const int* in_sizes, int n_in,
                              void* d_out, int out_size, void* d_ws, size_t ws_size,
                              hipStream_t stream) {
  const float* X = (const float*)d_in[0];
  const float* W = (const float*)d_in[1];
  const float* b = (const float*)d_in[2];
  const float* lam = (const float*)d_in[3];
  float* out = (float*)d_out;

  // ws layout: Xq 8MB | Wq 8MB | sX 32KB | sW 32KB
  const size_t qbytes = (size_t)SS * DD;
  const size_t need = 2 * qbytes + 2 * (size_t)SS * sizeof(float);
  if (ws_size >= need) {
    char* Xq = (char*)d_ws;
    char* Wq = Xq + qbytes;
    float* sX = (float*)(Wq + qbytes);
    float* sW = sX + SS;
    somfnn_quant<<<dim3(2 * SS), dim3(256), 0, stream>>>(X, W, Xq, Wq, sX, sW, (float4*)out);
    somfnn_gemm_i8<<<dim3(512), dim3(256), 0, stream>>>(Xq, Wq, sX, sW, b, lam, out);
  } else {
    hipMemsetAsync(out, 0, (size_t)SS * OO * sizeof(float), stream);
    somfnn_gemm_fb<<<dim3(512), dim3(256), 0, stream>>>(X, W, b, lam, out);
  }
}